// Round 7
// baseline (556.239 us; speedup 1.0000x reference)
//
#include <hip/hip_runtime.h>

#define N_NODES 100000
#define T_P 12
#define C_H 32
#define E_EDGES 3200000

#define NPB 256                 // nodes per bucket (dst>>8)
#define NB 391                  // ceil(N/256)
#define NBP (NB * NPB)          // padded node count = 100096
#define NC 256                  // edge chunks
#define CE 12500                // edges per chunk (NC*CE == E)
#define K_DEG 8

// ws layout (4B units), ~39.6 MB total:
//  P:256 | start:392 | tot:392 | histo:NB*NC | bp:NB*NC | degp:K_DEG*NBP | dinv:NBP
//  | y4:3*NBP float4 | rec:2*E (uint2) | agg4:3*NBP float4

__global__ void params_kernel(const float* __restrict__ wz, const float* __restrict__ bz,
                              const float* __restrict__ wh, const float* __restrict__ bh,
                              const float* __restrict__ lwz, const float* __restrict__ lbz,
                              const float* __restrict__ lwh, const float* __restrict__ lbh,
                              const float* __restrict__ att, float* __restrict__ P) {
    int o = threadIdx.x;
    if (o < C_H) {
        float az = 0.f, bzv = 0.f, ah = 0.f, bhv = 0.f;
        for (int c = 0; c < C_H; ++c) {
            float lz = lwz[o * 2 * C_H + c];
            float lh = lwh[o * 2 * C_H + c];
            az += wz[c] * lz;  bzv += bz[c] * lz;
            ah += wh[c] * lh;  bhv += bh[c] * lh;
        }
        P[16 + o]  = az;  P[48 + o]  = bzv + lbz[o];
        P[80 + o]  = ah;  P[112 + o] = bhv + lbh[o];
    }
    if (o == 0) {
        float m = -1e30f;
        for (int t = 0; t < T_P; ++t) m = fmaxf(m, att[t]);
        float e[T_P], s = 0.f;
        for (int t = 0; t < T_P; ++t) { e[t] = __expf(att[t] - m); s += e[t]; }
        float inv = 1.0f / s;
        for (int t = 0; t < T_P; ++t) P[t] = e[t] * inv;
    }
}

__global__ void hist_kernel(const int* __restrict__ dst, int* __restrict__ histo) {
    __shared__ int h[NB];
    int c = blockIdx.x;
    for (int i = threadIdx.x; i < NB; i += 1024) h[i] = 0;
    __syncthreads();
    const int* de = dst + c * CE;
    for (int i = threadIdx.x; i < CE; i += 1024)
        atomicAdd(&h[de[i] >> 8], 1);
    __syncthreads();
    for (int b = threadIdx.x; b < NB; b += 1024) histo[b * NC + c] = h[b];
}

__global__ void scan_bc_kernel(const int* __restrict__ histo, int* __restrict__ bp,
                               int* __restrict__ tot) {
    __shared__ int buf[NC];
    int b = blockIdx.x, t = threadIdx.x;
    int v = histo[b * NC + t];
    buf[t] = v;
    __syncthreads();
    for (int d = 1; d < NC; d <<= 1) {
        int u = (t >= d) ? buf[t - d] : 0;
        __syncthreads();
        buf[t] += u;
        __syncthreads();
    }
    bp[b * NC + t] = buf[t] - v;
    if (t == NC - 1) tot[b] = buf[t];
}

__global__ void scan_tot_kernel(const int* __restrict__ tot, int* __restrict__ start) {
    __shared__ int buf[512];
    int t = threadIdx.x;
    int v = (t < NB) ? tot[t] : 0;
    buf[t] = v;
    __syncthreads();
    for (int d = 1; d < 512; d <<= 1) {
        int u = (t >= d) ? buf[t - d] : 0;
        __syncthreads();
        buf[t] += u;
        __syncthreads();
    }
    if (t < NB) start[t] = buf[t] - v;
    if (t == NB - 1) start[NB] = buf[t];
}

__global__ void scatter_kernel(const int* __restrict__ src, const int* __restrict__ dst,
                               const float* __restrict__ w, const int* __restrict__ bp,
                               const int* __restrict__ start, uint2* __restrict__ rec) {
    __shared__ int cur[NB];
    int c = blockIdx.x;
    for (int b = threadIdx.x; b < NB; b += 1024) cur[b] = start[b] + bp[b * NC + c];
    __syncthreads();
    int e0 = c * CE;
    for (int i = threadIdx.x; i < CE; i += 1024) {
        int e = e0 + i;
        int d = dst[e];
        int b = d >> 8;
        int pos = atomicAdd(&cur[b], 1);
        unsigned lo = (unsigned)src[e] | ((unsigned)(d & 255) << 17);
        unsigned long long v = ((unsigned long long)__float_as_uint(w[e]) << 32) | lo;
        __builtin_nontemporal_store(v, (unsigned long long*)(rec + pos));
    }
}

__global__ void deg_kernel(const uint2* __restrict__ rec, const int* __restrict__ start,
                           float* __restrict__ degp) {
    __shared__ float ldeg[NPB];
    int b = blockIdx.x / K_DEG, k = blockIdx.x % K_DEG;
    for (int i = threadIdx.x; i < NPB; i += 256) ldeg[i] = 0.f;
    __syncthreads();
    int s0 = start[b], cnt = start[b + 1] - s0;
    int a = s0 + (int)((long long)cnt * k / K_DEG);
    int z = s0 + (int)((long long)cnt * (k + 1) / K_DEG);
    for (int i = a + threadIdx.x; i < z; i += 256) {
        unsigned long long rv = __builtin_nontemporal_load((const unsigned long long*)(rec + i));
        atomicAdd(&ldeg[((unsigned)rv) >> 17], __uint_as_float((unsigned)(rv >> 32)));
    }
    __syncthreads();
    float* dp = degp + (size_t)k * NBP + (size_t)b * NPB;
    for (int i = threadIdx.x; i < NPB; i += 256) dp[i] = ldeg[i];
}

// dinv = rsqrt(1+deg); y planes: y4[p*NBP+n] = dinv[n] * x[n, 4p..4p+3]
__global__ void dinvy_kernel(const float* __restrict__ degp, const float* __restrict__ x,
                             float* __restrict__ dinv, float4* __restrict__ y4) {
    int n = blockIdx.x * 256 + threadIdx.x;
    if (n >= NBP) return;
    if (n >= N_NODES) { dinv[n] = 0.f; return; }
    float d = 1.f;   // self-loop
#pragma unroll
    for (int k = 0; k < K_DEG; ++k) d += degp[(size_t)k * NBP + n];
    float di = rsqrtf(d);
    dinv[n] = di;
    const float4* xr = (const float4*)(x + (size_t)n * T_P);
    float4 a0 = xr[0], a1 = xr[1], a2 = xr[2];
    a0.x *= di; a0.y *= di; a0.z *= di; a0.w *= di;
    a1.x *= di; a1.y *= di; a1.z *= di; a1.w *= di;
    a2.x *= di; a2.y *= di; a2.z *= di; a2.w *= di;
    y4[n] = a0; y4[NBP + n] = a1; y4[2 * NBP + n] = a2;
}

// one dispatch per plane p (sequential): random reads confined to one 1.6MB
// plane, resident in every XCD L2. 1024 thr; pair i / i+1024, stride 2048
// (exact tiling of [s0,s1)).
__global__ void agg_kernel(const uint2* __restrict__ rec, const int* __restrict__ start,
                           const float4* __restrict__ y4, float4* __restrict__ agg4,
                           int p) {
    __shared__ float acc[NPB * 5];   // stride 5: kills power-of-2 bank aliasing
    int b = blockIdx.x;
    const float4* yp = y4 + (size_t)p * NBP;
    for (int i = threadIdx.x; i < NPB * 5; i += 1024) acc[i] = 0.f;
    __syncthreads();
    int s0 = start[b], s1 = start[b + 1];
    for (int i = s0 + threadIdx.x; i < s1; i += 2048) {
        unsigned long long rva = __builtin_nontemporal_load((const unsigned long long*)(rec + i));
        int ib = i + 1024;
        unsigned long long rvb = (ib < s1)
            ? __builtin_nontemporal_load((const unsigned long long*)(rec + ib))
            : 0ULL;                                   // s=0, dl=0, w=0 -> adds 0
        unsigned ra = (unsigned)rva; float wa = __uint_as_float((unsigned)(rva >> 32));
        unsigned rb = (unsigned)rvb; float wb = __uint_as_float((unsigned)(rvb >> 32));
        float4 va = yp[ra & 0x1FFFF];
        float4 vb = yp[rb & 0x1FFFF];
        float* aa = acc + (ra >> 17) * 5;
        float* ab = acc + (rb >> 17) * 5;
        atomicAdd(aa + 0, wa * va.x);
        atomicAdd(aa + 1, wa * va.y);
        atomicAdd(aa + 2, wa * va.z);
        atomicAdd(aa + 3, wa * va.w);
        atomicAdd(ab + 0, wb * vb.x);
        atomicAdd(ab + 1, wb * vb.y);
        atomicAdd(ab + 2, wb * vb.z);
        atomicAdd(ab + 3, wb * vb.w);
    }
    __syncthreads();
    float4* ap = agg4 + (size_t)p * NBP + (size_t)b * NPB;
    for (int dl = threadIdx.x; dl < NPB; dl += 1024)
        ap[dl] = make_float4(acc[dl * 5], acc[dl * 5 + 1], acc[dl * 5 + 2], acc[dl * 5 + 3]);
}

__global__ void final_kernel(const float4* __restrict__ y4, const float* __restrict__ dinv,
                             const float4* __restrict__ agg4, const float* __restrict__ P,
                             const float* __restrict__ head_w, const float* __restrict__ head_b,
                             float* __restrict__ out) {
    int tid = blockIdx.x * blockDim.x + threadIdx.x;
    int n = tid >> 5;
    int o = tid & 31;
    if (n >= N_NODES) return;
    float Az = P[16 + o], Bz = P[48 + o], Ah = P[80 + o], Bh = P[112 + o];
    float din = dinv[n];
    float h = 0.f;
#pragma unroll
    for (int p = 0; p < 3; ++p) {
        float4 yv = y4[(size_t)p * NBP + n];
        float4 av = agg4[(size_t)p * NBP + n];
        float ys[4] = {yv.x, yv.y, yv.z, yv.w};
        float as[4] = {av.x, av.y, av.z, av.w};
#pragma unroll
        for (int q = 0; q < 4; ++q) {
            float a = din * (ys[q] + as[q]);
            float oz = 1.f / (1.f + __expf(a * Az + Bz));      // 1 - sigmoid
            float v  = a * Ah + Bh;
            float th = 1.f - 2.f / (1.f + __expf(2.f * v));    // tanh
            h += P[p * 4 + q] * oz * th;
        }
    }
    h = fmaxf(h, 0.f) * head_w[o];
#pragma unroll
    for (int m = 16; m > 0; m >>= 1) h += __shfl_xor(h, m, 32);
    if (o == 0) out[n] = h + head_b[0];
}

extern "C" void kernel_launch(void* const* d_in, const int* in_sizes, int n_in,
                              void* d_out, int out_size, void* d_ws, size_t ws_size,
                              hipStream_t stream) {
    const float* x    = (const float*)d_in[0];
    const int*   ei   = (const int*)d_in[1];
    const float* ew   = (const float*)d_in[2];
    const float* w_z  = (const float*)d_in[3];
    const float* b_z  = (const float*)d_in[4];
    const float* w_h  = (const float*)d_in[7];
    const float* b_h  = (const float*)d_in[8];
    const float* lw_z = (const float*)d_in[9];
    const float* lb_z = (const float*)d_in[10];
    const float* lw_h = (const float*)d_in[13];
    const float* lb_h = (const float*)d_in[14];
    const float* att  = (const float*)d_in[15];
    const float* hw   = (const float*)d_in[16];
    const float* hb   = (const float*)d_in[17];
    float* out = (float*)d_out;

    int*   wsi   = (int*)d_ws;
    float* P     = (float*)wsi;                 // 256
    int*   start = wsi + 256;                   // 392
    int*   tot   = wsi + 648;                   // 392
    int*   histo = wsi + 1040;                  // NB*NC
    int*   bp    = histo + NB * NC;             // NB*NC
    float* degp  = (float*)(bp + NB * NC);      // K_DEG*NBP
    float* dinv  = degp + (size_t)K_DEG * NBP;  // NBP
    float4* y4   = (float4*)(dinv + NBP);       // 3*NBP float4 (16B-aligned offset)
    uint2* rec   = (uint2*)(y4 + 3 * (size_t)NBP);    // E
    float4* agg4 = (float4*)(rec + E_EDGES);    // 3*NBP float4

    const int* src = ei;
    const int* dst = ei + E_EDGES;

    params_kernel<<<1, 64, 0, stream>>>(w_z, b_z, w_h, b_h, lw_z, lb_z, lw_h, lb_h, att, P);
    hist_kernel<<<NC, 1024, 0, stream>>>(dst, histo);
    scan_bc_kernel<<<NB, NC, 0, stream>>>(histo, bp, tot);
    scan_tot_kernel<<<1, 512, 0, stream>>>(tot, start);
    scatter_kernel<<<NC, 1024, 0, stream>>>(src, dst, ew, bp, start, rec);
    deg_kernel<<<NB * K_DEG, 256, 0, stream>>>(rec, start, degp);
    dinvy_kernel<<<(NBP + 255) / 256, 256, 0, stream>>>(degp, x, dinv, y4);
    agg_kernel<<<NB, 1024, 0, stream>>>(rec, start, y4, agg4, 0);
    agg_kernel<<<NB, 1024, 0, stream>>>(rec, start, y4, agg4, 1);
    agg_kernel<<<NB, 1024, 0, stream>>>(rec, start, y4, agg4, 2);
    final_kernel<<<(N_NODES * C_H + 255) / 256, 256, 0, stream>>>(y4, dinv, agg4, P, hw, hb, out);
}